// Round 5
// baseline (279.161 us; speedup 1.0000x reference)
//
#include <hip/hip_runtime.h>
#include <hip/hip_fp16.h>

// GMM (MoNet) graph conv, 2 layers. Commuted-GEMM gather: h[n] = sum_k (sum_e g[e,k] x[col e]) W1[k].
// R4 -> R5: same algorithm, reparallelized. One WAVE per node (grid N/4 blocks, was N/64 with
// 16 serial nodes/wave -> occupancy 26%, 0.8 TB/s). W read from global (L1-resident 24 KB)
// instead of 24 KB LDS stage; LDS now 3 KB/block. gauss stored fp16 (8 B/edge vs 16).

#define KK 3

__global__ void prep_kernel(const float* __restrict__ p, const float* __restrict__ mu,
                            const float* __restrict__ sigma, float2* __restrict__ gaussh,
                            const float* __restrict__ x, __half* __restrict__ xh,
                            int E, int NX8) {
    int i = blockIdx.x * blockDim.x + threadIdx.x;
    if (i < E) {
        float p0 = p[2 * i], p1 = p[2 * i + 1];
        float g[KK];
#pragma unroll
        for (int k = 0; k < KK; ++k) {
            float m0 = mu[2 * k], m1 = mu[2 * k + 1];
            float s0 = sigma[2 * k], s1 = sigma[2 * k + 1];
            float d0 = p0 - m0, d1 = p1 - m1;
            float q = (d0 * d0) / (s0 * s0) + (d1 * d1) / (s1 * s1);
            g[k] = __expf(-0.5f * q);
        }
        union { __half h[4]; float2 v; } o;
        o.h[0] = __float2half(g[0]); o.h[1] = __float2half(g[1]);
        o.h[2] = __float2half(g[2]); o.h[3] = __float2half(0.f);
        gaussh[i] = o.v;
    }
    if (i < NX8) {   // cast 8 floats -> 8 halves per thread
        float4 v0 = ((const float4*)x)[2 * i];
        float4 v1 = ((const float4*)x)[2 * i + 1];
        union { __half h[8]; float4 v; } o;
        o.h[0] = __float2half(v0.x); o.h[1] = __float2half(v0.y);
        o.h[2] = __float2half(v0.z); o.h[3] = __float2half(v0.w);
        o.h[4] = __float2half(v1.x); o.h[5] = __float2half(v1.y);
        o.h[6] = __float2half(v1.z); o.h[7] = __float2half(v1.w);
        ((float4*)xh)[i] = o.v;
    }
}

// One wave per node. Phase 1: lane = (esub, f2): gathers half2 of features for edge subset,
// 16-edge unroll (8 or 4 independent chains in flight), shfl_xor reduce across esub.
// Phase 2: out[n,o] = sum_j s[j] * W[j,o]; lane = (jpart, o); W from global (L1), s broadcast LDS.
template <int F, int H, bool OUT_HALF>
__global__ __launch_bounds__(256) void fused_conv(
    const int* __restrict__ row_ptr, const int* __restrict__ col_idx,
    const float2* __restrict__ gaussh, const __half* __restrict__ xh,
    const float* __restrict__ W, void* __restrict__ yout, int N) {
    constexpr int J    = KK * F;       // 192 / 96
    constexpr int SUBW = F / 2;        // lanes covering one row: 32 / 16
    constexpr int ESUB = 64 / SUBW;    // edges in parallel: 2 / 4
    constexpr int NIT  = 16 / ESUB;    // unrolled steps per 16 edges: 8 / 4
    constexpr int JROW = J + 2;        // padded LDS row (floats, even -> float2 aligned)

    __shared__ float sL[4][JROW];

    const int wv   = threadIdx.x >> 6;
    const int lane = threadIdx.x & 63;
    const int n    = blockIdx.x * 4 + wv;

    const int f2   = lane & (SUBW - 1);   // half2 feature index
    const int esub = lane >> (F == 64 ? 5 : 4);

    const __half2* x2 = (const __half2*)xh;

    float2 a0 = {0.f, 0.f}, a1 = {0.f, 0.f}, a2 = {0.f, 0.f};

    if (n < N) {
        int e0 = row_ptr[n], e1 = row_ptr[n + 1];
        int e = e0;
        for (; e + 16 <= e1; e += 16) {
            int cols[NIT];
            float2 graw[NIT];
#pragma unroll
            for (int it = 0; it < NIT; ++it) cols[it] = col_idx[e + it * ESUB + esub];
#pragma unroll
            for (int it = 0; it < NIT; ++it) graw[it] = gaussh[e + it * ESUB + esub];
            __half2 xr[NIT];
#pragma unroll
            for (int it = 0; it < NIT; ++it) xr[it] = x2[(size_t)cols[it] * SUBW + f2];
#pragma unroll
            for (int it = 0; it < NIT; ++it) {
                union { float2 v; __half h[4]; } u; u.v = graw[it];
                float g0 = __half2float(u.h[0]);
                float g1 = __half2float(u.h[1]);
                float g2 = __half2float(u.h[2]);
                float2 xf = __half22float2(xr[it]);
                a0.x = fmaf(g0, xf.x, a0.x); a0.y = fmaf(g0, xf.y, a0.y);
                a1.x = fmaf(g1, xf.x, a1.x); a1.y = fmaf(g1, xf.y, a1.y);
                a2.x = fmaf(g2, xf.x, a2.x); a2.y = fmaf(g2, xf.y, a2.y);
            }
        }
        for (; e < e1; e += ESUB) {
            int ee = e + esub;
            bool ok = ee < e1;
            int c = ok ? col_idx[ee] : 0;
            float g0 = 0.f, g1 = 0.f, g2 = 0.f;
            if (ok) {
                union { float2 v; __half h[4]; } u; u.v = gaussh[ee];
                g0 = __half2float(u.h[0]); g1 = __half2float(u.h[1]); g2 = __half2float(u.h[2]);
            }
            float2 xf = __half22float2(x2[(size_t)c * SUBW + f2]);
            a0.x = fmaf(g0, xf.x, a0.x); a0.y = fmaf(g0, xf.y, a0.y);
            a1.x = fmaf(g1, xf.x, a1.x); a1.y = fmaf(g1, xf.y, a1.y);
            a2.x = fmaf(g2, xf.x, a2.x); a2.y = fmaf(g2, xf.y, a2.y);
        }
    }

    // reduce across edge subgroups (lanes with same f2)
#pragma unroll
    for (int off = SUBW; off < 64; off <<= 1) {
        a0.x += __shfl_xor(a0.x, off, 64); a0.y += __shfl_xor(a0.y, off, 64);
        a1.x += __shfl_xor(a1.x, off, 64); a1.y += __shfl_xor(a1.y, off, 64);
        a2.x += __shfl_xor(a2.x, off, 64); a2.y += __shfl_xor(a2.y, off, 64);
    }
    if (lane < SUBW) {
        float2* row = (float2*)sL[wv];
        row[0 * SUBW + f2] = a0;
        row[1 * SUBW + f2] = a1;
        row[2 * SUBW + f2] = a2;
    }
    __syncthreads();

    // phase 2: this wave computes its own node's H outputs
    {
        constexpr int P  = 64 / H;       // j partitions: 2 (H=32) / 4 (H=16)
        constexpr int JP = J / P;        // j per partition: 96 / 24
        const int o  = lane & (H - 1);
        const int pp = lane >> (H == 32 ? 5 : 4);
        const float* sv = sL[wv] + pp * JP;
        const float* Wp = W + (size_t)pp * JP * H + o;
        float acc = 0.f;
#pragma unroll 4
        for (int jj = 0; jj < JP; ++jj)
            acc = fmaf(sv[jj], Wp[(size_t)jj * H], acc);
#pragma unroll
        for (int off = H; off < 64; off <<= 1)
            acc += __shfl_xor(acc, off, 64);
        if (n < N && lane < H) {
            if constexpr (OUT_HALF) ((__half*)yout)[(size_t)n * H + o] = __float2half(acc);
            else                    ((float*)yout)[(size_t)n * H + o] = acc;
        }
    }
}

extern "C" void kernel_launch(void* const* d_in, const int* in_sizes, int n_in,
                              void* d_out, int out_size, void* d_ws, size_t ws_size,
                              hipStream_t stream) {
    const int* row_ptr  = (const int*)d_in[0];
    const int* col_idx  = (const int*)d_in[1];
    const float* x      = (const float*)d_in[2];
    const float* p      = (const float*)d_in[3];
    const float* mu     = (const float*)d_in[4];
    const float* sigma  = (const float*)d_in[5];
    const float* W1     = (const float*)d_in[6];
    const float* W2     = (const float*)d_in[7];

    const int N = in_sizes[0] - 1;
    const int E = in_sizes[1];

    float2* gaussh = (float2*)d_ws;                       // E half4 (8 B each)
    __half* xh     = (__half*)(gaussh + (size_t)E);       // N*64 fp16
    __half* hh     = xh + (size_t)N * 64;                 // N*32 fp16
    float*  out    = (float*)d_out;                       // N*16 f32

    const int B = 256;
    const int NX8 = N * 8;
    const int prep_n = (E > NX8 ? E : NX8);

    prep_kernel<<<(prep_n + B - 1) / B, B, 0, stream>>>(p, mu, sigma, gaussh, x, xh, E, NX8);

    const int nblocks = (N + 3) / 4;
    fused_conv<64, 32, true><<<nblocks, B, 0, stream>>>(row_ptr, col_idx, gaussh, xh, W1, (void*)hh, N);
    fused_conv<32, 16, false><<<nblocks, B, 0, stream>>>(row_ptr, col_idx, gaussh, hh, W2, (void*)out, N);
}

// Round 6
// 227.142 us; speedup vs baseline: 1.2290x; 1.2290x over previous
//
#include <hip/hip_runtime.h>
#include <hip/hip_fp16.h>

// GMM (MoNet) graph conv, 2 layers. Commuted-GEMM gather: h[n] = sum_k (sum_e g[e,k] x[col e]) W1[k].
// R5 -> R6: same algorithm + fusion, but R3-style MLP. Phase 1: thread = (node, 16B feature
// chunk), 8-edge batching -> ~8 KB outstanding loads per wave (R5 had 2 KB -> latency-bound,
// 0.65 TB/s). Phase 2 in-block GEMM: s from LDS (pad +4 -> conflict-free b128), W via L1.

#define KK 3

__global__ void prep_kernel(const float* __restrict__ p, const float* __restrict__ mu,
                            const float* __restrict__ sigma, float2* __restrict__ gaussh,
                            const float* __restrict__ x, __half* __restrict__ xh,
                            int E, int NX8) {
    int i = blockIdx.x * blockDim.x + threadIdx.x;
    if (i < E) {
        float p0 = p[2 * i], p1 = p[2 * i + 1];
        float g[KK];
#pragma unroll
        for (int k = 0; k < KK; ++k) {
            float m0 = mu[2 * k], m1 = mu[2 * k + 1];
            float s0 = sigma[2 * k], s1 = sigma[2 * k + 1];
            float d0 = p0 - m0, d1 = p1 - m1;
            float q = (d0 * d0) / (s0 * s0) + (d1 * d1) / (s1 * s1);
            g[k] = __expf(-0.5f * q);
        }
        union { __half h[4]; float2 v; } o;
        o.h[0] = __float2half(g[0]); o.h[1] = __float2half(g[1]);
        o.h[2] = __float2half(g[2]); o.h[3] = __float2half(0.f);
        gaussh[i] = o.v;
    }
    if (i < NX8) {
        float4 v0 = ((const float4*)x)[2 * i];
        float4 v1 = ((const float4*)x)[2 * i + 1];
        union { __half h[8]; float4 v; } o;
        o.h[0] = __float2half(v0.x); o.h[1] = __float2half(v0.y);
        o.h[2] = __float2half(v0.z); o.h[3] = __float2half(v0.w);
        o.h[4] = __float2half(v1.x); o.h[5] = __float2half(v1.y);
        o.h[6] = __float2half(v1.z); o.h[7] = __float2half(v1.w);
        ((float4*)xh)[i] = o.v;
    }
}

__device__ __forceinline__ void unpack8(float4 raw, float* f) {
    union { float4 v; __half2 h2[4]; } u;
    u.v = raw;
#pragma unroll
    for (int q = 0; q < 4; ++q) {
        float2 t = __half22float2(u.h2[q]);
        f[2 * q] = t.x; f[2 * q + 1] = t.y;
    }
}

// Phase 1: thread = (node nl, chunk ch of 8 halves). s[j=k*F+f] accumulated fp32 in regs.
// Phase 2: thread = (node, 4 outputs). y = s . W  with s broadcast from LDS, W via L1.
template <int F, int H, bool OUT_HALF>
__global__ __launch_bounds__(256) void fused_conv(
    const int* __restrict__ row_ptr, const int* __restrict__ col_idx,
    const float2* __restrict__ gaussh, const __half* __restrict__ xh,
    const float* __restrict__ W, void* __restrict__ yout, int N) {
    constexpr int TPN   = F / 8;        // threads per node, phase 1: 8 / 4
    constexpr int NODES = 256 / TPN;    // 32 / 64
    constexpr int J     = KK * F;       // 192 / 96
    constexpr int JPAD  = J + 4;        // pad: stride%32 = 4 -> b128 reads hit distinct banks

    __shared__ float sL[NODES * JPAD];

    const int tid = threadIdx.x;
    const int nl  = tid / TPN;
    const int ch  = tid % TPN;
    const int n0  = blockIdx.x * NODES;
    const int n   = n0 + nl;

    float a0[8], a1[8], a2[8];
#pragma unroll
    for (int q = 0; q < 8; ++q) { a0[q] = 0.f; a1[q] = 0.f; a2[q] = 0.f; }

    const float4* x4 = (const float4*)xh;   // 8 halves per float4

    if (n < N) {
        int e0 = row_ptr[n], e1 = row_ptr[n + 1];
        int e = e0;
        for (; e + 8 <= e1; e += 8) {
            int cols[8];
            float2 gr[8];
            float4 xr[8];
#pragma unroll
            for (int j = 0; j < 8; ++j) cols[j] = col_idx[e + j];
#pragma unroll
            for (int j = 0; j < 8; ++j) gr[j] = gaussh[e + j];
#pragma unroll
            for (int j = 0; j < 8; ++j) xr[j] = x4[(size_t)cols[j] * TPN + ch];
#pragma unroll
            for (int j = 0; j < 8; ++j) {
                union { float2 v; __half2 h2[2]; } ug; ug.v = gr[j];
                float2 gab = __half22float2(ug.h2[0]);
                float2 gc_ = __half22float2(ug.h2[1]);
                float f[8];
                unpack8(xr[j], f);
#pragma unroll
                for (int q = 0; q < 8; ++q) {
                    a0[q] = fmaf(gab.x, f[q], a0[q]);
                    a1[q] = fmaf(gab.y, f[q], a1[q]);
                    a2[q] = fmaf(gc_.x, f[q], a2[q]);
                }
            }
        }
        for (; e < e1; ++e) {
            int c = col_idx[e];
            union { float2 v; __half2 h2[2]; } ug; ug.v = gaussh[e];
            float2 gab = __half22float2(ug.h2[0]);
            float2 gc_ = __half22float2(ug.h2[1]);
            float f[8];
            unpack8(x4[(size_t)c * TPN + ch], f);
#pragma unroll
            for (int q = 0; q < 8; ++q) {
                a0[q] = fmaf(gab.x, f[q], a0[q]);
                a1[q] = fmaf(gab.y, f[q], a1[q]);
                a2[q] = fmaf(gc_.x, f[q], a2[q]);
            }
        }
    }

    {
        float* srow = sL + nl * JPAD + ch * 8;
        ((float4*)(srow + 0 * F))[0] = *(float4*)&a0[0];
        ((float4*)(srow + 0 * F))[1] = *(float4*)&a0[4];
        ((float4*)(srow + 1 * F))[0] = *(float4*)&a1[0];
        ((float4*)(srow + 1 * F))[1] = *(float4*)&a1[4];
        ((float4*)(srow + 2 * F))[0] = *(float4*)&a2[0];
        ((float4*)(srow + 2 * F))[1] = *(float4*)&a2[4];
    }
    __syncthreads();

    // phase 2: y[n2, o0..o0+3] = sum_j s[n2][j] * W[j][o0..o0+3]
    {
        constexpr int TP2 = H / 4;           // threads per node: 8 / 4
        const int n2l = tid / TP2;
        const int o0  = (tid % TP2) * 4;
        const int n2  = n0 + n2l;
        const float* s2 = sL + n2l * JPAD;

        float4 acc = {0.f, 0.f, 0.f, 0.f};
#pragma unroll 4
        for (int j = 0; j < J; j += 4) {
            float4 sv = *(const float4*)(s2 + j);
            float4 w0 = *(const float4*)(W + (size_t)(j + 0) * H + o0);
            float4 w1 = *(const float4*)(W + (size_t)(j + 1) * H + o0);
            float4 w2 = *(const float4*)(W + (size_t)(j + 2) * H + o0);
            float4 w3 = *(const float4*)(W + (size_t)(j + 3) * H + o0);
            acc.x = fmaf(sv.x, w0.x, acc.x); acc.y = fmaf(sv.x, w0.y, acc.y);
            acc.z = fmaf(sv.x, w0.z, acc.z); acc.w = fmaf(sv.x, w0.w, acc.w);
            acc.x = fmaf(sv.y, w1.x, acc.x); acc.y = fmaf(sv.y, w1.y, acc.y);
            acc.z = fmaf(sv.y, w1.z, acc.z); acc.w = fmaf(sv.y, w1.w, acc.w);
            acc.x = fmaf(sv.z, w2.x, acc.x); acc.y = fmaf(sv.z, w2.y, acc.y);
            acc.z = fmaf(sv.z, w2.z, acc.z); acc.w = fmaf(sv.z, w2.w, acc.w);
            acc.x = fmaf(sv.w, w3.x, acc.x); acc.y = fmaf(sv.w, w3.y, acc.y);
            acc.z = fmaf(sv.w, w3.z, acc.z); acc.w = fmaf(sv.w, w3.w, acc.w);
        }
        if (n2 < N) {
            if constexpr (OUT_HALF) {
                union { __half h[4]; float2 v; } o;
                o.h[0] = __float2half(acc.x); o.h[1] = __float2half(acc.y);
                o.h[2] = __float2half(acc.z); o.h[3] = __float2half(acc.w);
                *(float2*)((__half*)yout + (size_t)n2 * H + o0) = o.v;
            } else {
                *(float4*)((float*)yout + (size_t)n2 * H + o0) = acc;
            }
        }
    }
}

extern "C" void kernel_launch(void* const* d_in, const int* in_sizes, int n_in,
                              void* d_out, int out_size, void* d_ws, size_t ws_size,
                              hipStream_t stream) {
    const int* row_ptr  = (const int*)d_in[0];
    const int* col_idx  = (const int*)d_in[1];
    const float* x      = (const float*)d_in[2];
    const float* p      = (const float*)d_in[3];
    const float* mu     = (const float*)d_in[4];
    const float* sigma  = (const float*)d_in[5];
    const float* W1     = (const float*)d_in[6];
    const float* W2     = (const float*)d_in[7];

    const int N = in_sizes[0] - 1;
    const int E = in_sizes[1];

    float2* gaussh = (float2*)d_ws;                       // E half4 (8 B each)
    __half* xh     = (__half*)(gaussh + (size_t)E);       // N*64 fp16
    __half* hh     = xh + (size_t)N * 64;                 // N*32 fp16
    float*  out    = (float*)d_out;                       // N*16 f32

    const int B = 256;
    const int NX8 = N * 8;
    const int prep_n = (E > NX8 ? E : NX8);

    prep_kernel<<<(prep_n + B - 1) / B, B, 0, stream>>>(p, mu, sigma, gaussh, x, xh, E, NX8);

    fused_conv<64, 32, true><<<(N + 31) / 32, B, 0, stream>>>(row_ptr, col_idx, gaussh, xh, W1, (void*)hh, N);
    fused_conv<32, 16, false><<<(N + 63) / 64, B, 0, stream>>>(row_ptr, col_idx, gaussh, hh, W2, (void*)out, N);
}

// Round 7
// 212.604 us; speedup vs baseline: 1.3131x; 1.0684x over previous
//
#include <hip/hip_runtime.h>
#include <hip/hip_fp16.h>

// GMM (MoNet) graph conv, 2 layers. Commuted-GEMM: h[n] = (sum_e g[e,k] x[col e]) . W1.
// R6 -> R7: DE-fused. R3's proven gather structure (no LDS, occ 52%, 5.5 TB/s) vs R6's
// fused (25KB LDS, occ 28%, 2.1 TB/s): fusion tax > the 77 MB round-trip it saves.
// Pipeline: prep -> gather_s<64> (s1[N,192] fp16) -> gemm (h fp16) -> gather_s<32> -> gemm (out).
// GEMM: 4 nodes x 4 outputs per thread: 16 FMA per W-float4, else L1-BW-bound on W re-reads.

#define KK 3

__global__ void prep_kernel(const float* __restrict__ p, const float* __restrict__ mu,
                            const float* __restrict__ sigma, float2* __restrict__ gaussh,
                            const float* __restrict__ x, __half* __restrict__ xh,
                            int E, int NX8) {
    int i = blockIdx.x * blockDim.x + threadIdx.x;
    if (i < E) {
        float p0 = p[2 * i], p1 = p[2 * i + 1];
        float g[KK];
#pragma unroll
        for (int k = 0; k < KK; ++k) {
            float m0 = mu[2 * k], m1 = mu[2 * k + 1];
            float s0 = sigma[2 * k], s1 = sigma[2 * k + 1];
            float d0 = p0 - m0, d1 = p1 - m1;
            float q = (d0 * d0) / (s0 * s0) + (d1 * d1) / (s1 * s1);
            g[k] = __expf(-0.5f * q);
        }
        union { __half h[4]; float2 v; } o;
        o.h[0] = __float2half(g[0]); o.h[1] = __float2half(g[1]);
        o.h[2] = __float2half(g[2]); o.h[3] = __float2half(0.f);
        gaussh[i] = o.v;
    }
    if (i < NX8) {
        float4 v0 = ((const float4*)x)[2 * i];
        float4 v1 = ((const float4*)x)[2 * i + 1];
        union { __half h[8]; float4 v; } o;
        o.h[0] = __float2half(v0.x); o.h[1] = __float2half(v0.y);
        o.h[2] = __float2half(v0.z); o.h[3] = __float2half(v0.w);
        o.h[4] = __float2half(v1.x); o.h[5] = __float2half(v1.y);
        o.h[6] = __float2half(v1.z); o.h[7] = __float2half(v1.w);
        ((float4*)xh)[i] = o.v;
    }
}

__device__ __forceinline__ void unpack8(float4 raw, float* f) {
    union { float4 v; __half2 h2[4]; } u;
    u.v = raw;
#pragma unroll
    for (int q = 0; q < 4; ++q) {
        float2 t = __half22float2(u.h2[q]);
        f[2 * q] = t.x; f[2 * q + 1] = t.y;
    }
}

// s[n, k*F + f] = sum_e g[e,k] * xh[col e, f].  Thread = (node, 8-feature chunk).
// Zero LDS, fp32 accumulate, 8-edge batching (~8KB outstanding/wave), fp16 output.
template <int F>
__global__ __launch_bounds__(256) void gather_s(
    const int* __restrict__ row_ptr, const int* __restrict__ col_idx,
    const float2* __restrict__ gaussh, const __half* __restrict__ xh,
    __half* __restrict__ s, int N) {
    constexpr int TPN = F / 8;          // threads per node: 8 / 4
    constexpr int J   = KK * F;         // 192 / 96

    const int t  = blockIdx.x * 256 + threadIdx.x;
    const int n  = t / TPN;
    const int ch = t % TPN;
    if (n >= N) return;

    float a0[8], a1[8], a2[8];
#pragma unroll
    for (int q = 0; q < 8; ++q) { a0[q] = 0.f; a1[q] = 0.f; a2[q] = 0.f; }

    const float4* x4 = (const float4*)xh;   // 8 halves per float4

    int e0 = row_ptr[n], e1 = row_ptr[n + 1];
    int e = e0;
    for (; e + 8 <= e1; e += 8) {
        int cols[8];
        float2 gr[8];
        float4 xr[8];
#pragma unroll
        for (int j = 0; j < 8; ++j) cols[j] = col_idx[e + j];
#pragma unroll
        for (int j = 0; j < 8; ++j) gr[j] = gaussh[e + j];
#pragma unroll
        for (int j = 0; j < 8; ++j) xr[j] = x4[(size_t)cols[j] * TPN + ch];
#pragma unroll
        for (int j = 0; j < 8; ++j) {
            union { float2 v; __half2 h2[2]; } ug; ug.v = gr[j];
            float2 gab = __half22float2(ug.h2[0]);
            float2 gc_ = __half22float2(ug.h2[1]);
            float f[8];
            unpack8(xr[j], f);
#pragma unroll
            for (int q = 0; q < 8; ++q) {
                a0[q] = fmaf(gab.x, f[q], a0[q]);
                a1[q] = fmaf(gab.y, f[q], a1[q]);
                a2[q] = fmaf(gc_.x, f[q], a2[q]);
            }
        }
    }
    for (; e < e1; ++e) {
        int c = col_idx[e];
        union { float2 v; __half2 h2[2]; } ug; ug.v = gaussh[e];
        float2 gab = __half22float2(ug.h2[0]);
        float2 gc_ = __half22float2(ug.h2[1]);
        float f[8];
        unpack8(x4[(size_t)c * TPN + ch], f);
#pragma unroll
        for (int q = 0; q < 8; ++q) {
            a0[q] = fmaf(gab.x, f[q], a0[q]);
            a1[q] = fmaf(gab.y, f[q], a1[q]);
            a2[q] = fmaf(gc_.x, f[q], a2[q]);
        }
    }

    // pack + store: 3 float4s (8 halves each)
    __half* srow = s + (size_t)n * J + ch * 8;
    union { __half h[8]; float4 v; } o;
#pragma unroll
    for (int q = 0; q < 8; ++q) o.h[q] = __float2half(a0[q]);
    *(float4*)(srow + 0 * F) = o.v;
#pragma unroll
    for (int q = 0; q < 8; ++q) o.h[q] = __float2half(a1[q]);
    *(float4*)(srow + 1 * F) = o.v;
#pragma unroll
    for (int q = 0; q < 8; ++q) o.h[q] = __float2half(a2[q]);
    *(float4*)(srow + 2 * F) = o.v;
}

// y[n, o0..o0+3] = sum_j s[n,j] * W[j,o0..o0+3].  Thread = (NPT nodes, 4 outputs):
// one W float4 feeds 4*NPT FMAs (W L1 traffic /NPT).
template <int J, int H, int NPT, bool OUT_HALF>
__global__ void gemm_s(const __half* __restrict__ s, const float* __restrict__ W,
                       void* __restrict__ yout, int N) {
    constexpr int TP2 = H / 4;         // o-groups per node
    const int t   = blockIdx.x * blockDim.x + threadIdx.x;
    const int qd  = t / TP2;           // node-group index
    const int o0  = (t % TP2) * 4;
    const int n0  = qd * NPT;
    if (n0 >= N) return;

    float4 acc[NPT];
#pragma unroll
    for (int m = 0; m < NPT; ++m) acc[m] = {0.f, 0.f, 0.f, 0.f};

    for (int j0 = 0; j0 < J; j0 += 8) {
        float f[NPT][8];
#pragma unroll
        for (int m = 0; m < NPT; ++m) {
            float4 sr = ((const float4*)(s + (size_t)(n0 + m) * J))[j0 / 8];
            unpack8(sr, f[m]);
        }
#pragma unroll
        for (int q = 0; q < 8; ++q) {
            float4 w = *(const float4*)(W + (size_t)(j0 + q) * H + o0);
#pragma unroll
            for (int m = 0; m < NPT; ++m) {
                acc[m].x = fmaf(f[m][q], w.x, acc[m].x);
                acc[m].y = fmaf(f[m][q], w.y, acc[m].y);
                acc[m].z = fmaf(f[m][q], w.z, acc[m].z);
                acc[m].w = fmaf(f[m][q], w.w, acc[m].w);
            }
        }
    }

#pragma unroll
    for (int m = 0; m < NPT; ++m) {
        int n = n0 + m;
        if (n >= N) break;
        if constexpr (OUT_HALF) {
            union { __half h[4]; float2 v; } o;
            o.h[0] = __float2half(acc[m].x); o.h[1] = __float2half(acc[m].y);
            o.h[2] = __float2half(acc[m].z); o.h[3] = __float2half(acc[m].w);
            *(float2*)((__half*)yout + (size_t)n * H + o0) = o.v;
        } else {
            *(float4*)((float*)yout + (size_t)n * H + o0) = acc[m];
        }
    }
}

extern "C" void kernel_launch(void* const* d_in, const int* in_sizes, int n_in,
                              void* d_out, int out_size, void* d_ws, size_t ws_size,
                              hipStream_t stream) {
    const int* row_ptr  = (const int*)d_in[0];
    const int* col_idx  = (const int*)d_in[1];
    const float* x      = (const float*)d_in[2];
    const float* p      = (const float*)d_in[3];
    const float* mu     = (const float*)d_in[4];
    const float* sigma  = (const float*)d_in[5];
    const float* W1     = (const float*)d_in[6];
    const float* W2     = (const float*)d_in[7];

    const int N = in_sizes[0] - 1;
    const int E = in_sizes[1];

    float2* gaussh = (float2*)d_ws;                       // E * 8 B
    __half* xh     = (__half*)(gaussh + (size_t)E);       // N*64 fp16
    __half* hh     = xh + (size_t)N * 64;                 // N*32 fp16
    __half* s1     = hh + (size_t)N * 32;                 // N*192 fp16
    __half* s2     = s1 + (size_t)N * 192;                // N*96 fp16
    float*  out    = (float*)d_out;                       // N*16 f32

    const int B = 256;
    const int NX8 = N * 8;
    const int prep_n = (E > NX8 ? E : NX8);

    prep_kernel<<<(prep_n + B - 1) / B, B, 0, stream>>>(p, mu, sigma, gaussh, x, xh, E, NX8);

    // layer 1
    {
        long long T = (long long)N * 8;           // TPN=8
        gather_s<64><<<(int)((T + B - 1) / B), B, 0, stream>>>(row_ptr, col_idx, gaussh, xh, s1, N);
        long long T2 = (long long)((N + 3) / 4) * 8;   // NPT=4, TP2=8
        gemm_s<192, 32, 4, true><<<(int)((T2 + B - 1) / B), B, 0, stream>>>(s1, W1, (void*)hh, N);
    }
    // layer 2
    {
        long long T = (long long)N * 4;           // TPN=4
        gather_s<32><<<(int)((T + B - 1) / B), B, 0, stream>>>(row_ptr, col_idx, gaussh, hh, s2, N);
        long long T2 = (long long)((N + 1) / 2) * 4;   // NPT=2, TP2=4
        gemm_s<96, 16, 2, false><<<(int)((T2 + B - 1) / B), B, 0, stream>>>(s2, W2, (void*)out, N);
    }
}

// Round 8
// 179.478 us; speedup vs baseline: 1.5554x; 1.1846x over previous
//
#include <hip/hip_runtime.h>
#include <hip/hip_fp16.h>

// GMM (MoNet) graph conv, 2 layers. Commuted-GEMM: h[n] = (sum_e g[e,k] x[col e]) . W1.
// R7 -> R8: the VALU gemm_s kernels (42 us each, occupancy 20%, latency-bound) replaced by
// MFMA (v_mfma_f32_16x16x32_f16): wave = 16 nodes x 16 outputs, A-frag straight from
// contiguous fp16 s rows (A[m=lane&15][k=quad*8+j]), W pre-packed to B-frag order.
// Pipeline: prep + pack_w -> gather_s<64> -> gemm_mfma<192,32> -> gather_s<32> -> gemm_mfma<96,16>.

#define KK 3

using half8  = __attribute__((ext_vector_type(8))) _Float16;
using float4v = __attribute__((ext_vector_type(4))) float;

__global__ void prep_kernel(const float* __restrict__ p, const float* __restrict__ mu,
                            const float* __restrict__ sigma, float2* __restrict__ gaussh,
                            const float* __restrict__ x, __half* __restrict__ xh,
                            int E, int NX8) {
    int i = blockIdx.x * blockDim.x + threadIdx.x;
    if (i < E) {
        float p0 = p[2 * i], p1 = p[2 * i + 1];
        float g[KK];
#pragma unroll
        for (int k = 0; k < KK; ++k) {
            float m0 = mu[2 * k], m1 = mu[2 * k + 1];
            float s0 = sigma[2 * k], s1 = sigma[2 * k + 1];
            float d0 = p0 - m0, d1 = p1 - m1;
            float q = (d0 * d0) / (s0 * s0) + (d1 * d1) / (s1 * s1);
            g[k] = __expf(-0.5f * q);
        }
        union { __half h[4]; float2 v; } o;
        o.h[0] = __float2half(g[0]); o.h[1] = __float2half(g[1]);
        o.h[2] = __float2half(g[2]); o.h[3] = __float2half(0.f);
        gaussh[i] = o.v;
    }
    if (i < NX8) {
        float4 v0 = ((const float4*)x)[2 * i];
        float4 v1 = ((const float4*)x)[2 * i + 1];
        union { __half h[8]; float4 v; } o;
        o.h[0] = __float2half(v0.x); o.h[1] = __float2half(v0.y);
        o.h[2] = __float2half(v0.z); o.h[3] = __float2half(v0.w);
        o.h[4] = __float2half(v1.x); o.h[5] = __float2half(v1.y);
        o.h[6] = __float2half(v1.z); o.h[7] = __float2half(v1.w);
        ((float4*)xh)[i] = o.v;
    }
}

// Pack W ([J][H] row-major fp32) into MFMA B-fragment order (fp16):
// Bpack[((ot*KB + kb)*64 + lane)*8 + j] = W[(kb*32 + (lane>>4)*8 + j)][ot*16 + (lane&15)]
__global__ void pack_w(const float* __restrict__ W1, const float* __restrict__ W2,
                       __half* __restrict__ B1, __half* __restrict__ B2) {
    int t = blockIdx.x * blockDim.x + threadIdx.x;
    if (t < 6144) {                    // W1: J=192 (KB=6), H=32 (OT=2)
        int j = t & 7, lane = (t >> 3) & 63, grp = t >> 9;   // grp = ot*6+kb
        int ot = grp / 6, kb = grp % 6;
        int kidx = kb * 32 + (lane >> 4) * 8 + j;
        int o = ot * 16 + (lane & 15);
        B1[t] = __float2half(W1[kidx * 32 + o]);
    } else if (t < 6144 + 1536) {      // W2: J=96 (KB=3), H=16 (OT=1)
        int t2 = t - 6144;
        int j = t2 & 7, lane = (t2 >> 3) & 63, kb = t2 >> 9;
        int kidx = kb * 32 + (lane >> 4) * 8 + j;
        int o = lane & 15;
        B2[t2] = __float2half(W2[kidx * 16 + o]);
    }
}

__device__ __forceinline__ void unpack8(float4 raw, float* f) {
    union { float4 v; __half2 h2[4]; } u;
    u.v = raw;
#pragma unroll
    for (int q = 0; q < 4; ++q) {
        float2 t = __half22float2(u.h2[q]);
        f[2 * q] = t.x; f[2 * q + 1] = t.y;
    }
}

// s[n, k*F + f] = sum_e g[e,k] * xh[col e, f].  Thread = (node, 8-feature chunk).
// Zero LDS, fp32 accumulate, 8-edge batching (~8KB outstanding/wave), fp16 output.
template <int F>
__global__ __launch_bounds__(256) void gather_s(
    const int* __restrict__ row_ptr, const int* __restrict__ col_idx,
    const float2* __restrict__ gaussh, const __half* __restrict__ xh,
    __half* __restrict__ s, int N) {
    constexpr int TPN = F / 8;
    constexpr int J   = KK * F;

    const int t  = blockIdx.x * 256 + threadIdx.x;
    const int n  = t / TPN;
    const int ch = t % TPN;
    if (n >= N) return;

    float a0[8], a1[8], a2[8];
#pragma unroll
    for (int q = 0; q < 8; ++q) { a0[q] = 0.f; a1[q] = 0.f; a2[q] = 0.f; }

    const float4* x4 = (const float4*)xh;

    int e0 = row_ptr[n], e1 = row_ptr[n + 1];
    int e = e0;
    for (; e + 8 <= e1; e += 8) {
        int cols[8];
        float2 gr[8];
        float4 xr[8];
#pragma unroll
        for (int j = 0; j < 8; ++j) cols[j] = col_idx[e + j];
#pragma unroll
        for (int j = 0; j < 8; ++j) gr[j] = gaussh[e + j];
#pragma unroll
        for (int j = 0; j < 8; ++j) xr[j] = x4[(size_t)cols[j] * TPN + ch];
#pragma unroll
        for (int j = 0; j < 8; ++j) {
            union { float2 v; __half2 h2[2]; } ug; ug.v = gr[j];
            float2 gab = __half22float2(ug.h2[0]);
            float2 gc_ = __half22float2(ug.h2[1]);
            float f[8];
            unpack8(xr[j], f);
#pragma unroll
            for (int q = 0; q < 8; ++q) {
                a0[q] = fmaf(gab.x, f[q], a0[q]);
                a1[q] = fmaf(gab.y, f[q], a1[q]);
                a2[q] = fmaf(gc_.x, f[q], a2[q]);
            }
        }
    }
    for (; e < e1; ++e) {
        int c = col_idx[e];
        union { float2 v; __half2 h2[2]; } ug; ug.v = gaussh[e];
        float2 gab = __half22float2(ug.h2[0]);
        float2 gc_ = __half22float2(ug.h2[1]);
        float f[8];
        unpack8(x4[(size_t)c * TPN + ch], f);
#pragma unroll
        for (int q = 0; q < 8; ++q) {
            a0[q] = fmaf(gab.x, f[q], a0[q]);
            a1[q] = fmaf(gab.y, f[q], a1[q]);
            a2[q] = fmaf(gc_.x, f[q], a2[q]);
        }
    }

    __half* srow = s + (size_t)n * J + ch * 8;
    union { __half h[8]; float4 v; } o;
#pragma unroll
    for (int q = 0; q < 8; ++q) o.h[q] = __float2half(a0[q]);
    *(float4*)(srow + 0 * F) = o.v;
#pragma unroll
    for (int q = 0; q < 8; ++q) o.h[q] = __float2half(a1[q]);
    *(float4*)(srow + 1 * F) = o.v;
#pragma unroll
    for (int q = 0; q < 8; ++q) o.h[q] = __float2half(a2[q]);
    *(float4*)(srow + 2 * F) = o.v;
}

// y[N,H] = s[N,J] (fp16) x W (pre-packed B-frags). Wave = 16 nodes x 16 outputs.
// A-frag: lane reads s[n0 + (lane&15)][kb*32 + (lane>>4)*8 ..+7] (16B contiguous).
template <int J, int H, bool OUT_HALF>
__global__ __launch_bounds__(256) void gemm_mfma(
    const __half* __restrict__ s, const __half* __restrict__ Bpack,
    void* __restrict__ yout, int N) {
    constexpr int KB = J / 32;        // 6 / 3
    constexpr int OT = H / 16;        // 2 / 1

    const int lane = threadIdx.x & 63;
    const int gw   = (blockIdx.x * 256 + threadIdx.x) >> 6;
    const int nt   = gw / OT;
    const int ot   = gw % OT;
    const int n0   = nt * 16;
    if (n0 >= N) return;

    const int quad = lane >> 4;
    const int row  = lane & 15;

    half8 b[KB];
#pragma unroll
    for (int kb = 0; kb < KB; ++kb)
        b[kb] = ((const half8*)Bpack)[(ot * KB + kb) * 64 + lane];

    const half8* arow = (const half8*)(s + (size_t)(n0 + row) * J);

    float4v acc = {0.f, 0.f, 0.f, 0.f};
#pragma unroll
    for (int kb = 0; kb < KB; ++kb)
        acc = __builtin_amdgcn_mfma_f32_16x16x32_f16(arow[kb * 4 + quad], b[kb], acc, 0, 0, 0);

    // C/D layout: col = lane&15, row = quad*4 + reg
    const int col = row;
    const int r0  = quad * 4;
#pragma unroll
    for (int reg = 0; reg < 4; ++reg) {
        int n = n0 + r0 + reg;
        if constexpr (OUT_HALF)
            ((__half*)yout)[(size_t)n * H + ot * 16 + col] = __float2half(acc[reg]);
        else
            ((float*)yout)[(size_t)n * H + col] = acc[reg];
    }
}

extern "C" void kernel_launch(void* const* d_in, const int* in_sizes, int n_in,
                              void* d_out, int out_size, void* d_ws, size_t ws_size,
                              hipStream_t stream) {
    const int* row_ptr  = (const int*)d_in[0];
    const int* col_idx  = (const int*)d_in[1];
    const float* x      = (const float*)d_in[2];
    const float* p      = (const float*)d_in[3];
    const float* mu     = (const float*)d_in[4];
    const float* sigma  = (const float*)d_in[5];
    const float* W1     = (const float*)d_in[6];
    const float* W2     = (const float*)d_in[7];

    const int N = in_sizes[0] - 1;
    const int E = in_sizes[1];

    __half* B1pack = (__half*)d_ws;                       // 6144 halves (12 KB)
    __half* B2pack = B1pack + 6144;                       // 1536 halves (3 KB)
    float2* gaussh = (float2*)(B2pack + 1536);            // E * 8 B
    __half* xh     = (__half*)(gaussh + (size_t)E);       // N*64 fp16
    __half* hh     = xh + (size_t)N * 64;                 // N*32 fp16
    __half* s1     = hh + (size_t)N * 32;                 // N*192 fp16
    __half* s2     = s1 + (size_t)N * 192;                // N*96 fp16
    float*  out    = (float*)d_out;                       // N*16 f32

    const int B = 256;
    const int NX8 = N * 8;
    const int prep_n = (E > NX8 ? E : NX8);

    prep_kernel<<<(prep_n + B - 1) / B, B, 0, stream>>>(p, mu, sigma, gaussh, x, xh, E, NX8);
    pack_w<<<30, B, 0, stream>>>(W1, W2, B1pack, B2pack);

    // layer 1
    {
        long long T = (long long)N * 8;
        gather_s<64><<<(int)((T + B - 1) / B), B, 0, stream>>>(row_ptr, col_idx, gaussh, xh, s1, N);
        int waves = ((N + 15) / 16) * 2;                  // node-tiles * OT
        gemm_mfma<192, 32, true><<<(waves + 3) / 4, B, 0, stream>>>(s1, B1pack, (void*)hh, N);
    }
    // layer 2
    {
        long long T = (long long)N * 4;
        gather_s<32><<<(int)((T + B - 1) / B), B, 0, stream>>>(row_ptr, col_idx, gaussh, hh, s2, N);
        int waves = (N + 15) / 16;
        gemm_mfma<96, 16, false><<<(waves + 3) / 4, B, 0, stream>>>(s2, B2pack, (void*)out, N);
    }
}

// Round 9
// 156.799 us; speedup vs baseline: 1.7804x; 1.1446x over previous
//
#include <hip/hip_runtime.h>
#include <hip/hip_fp16.h>

// GMM (MoNet) graph conv, 2 layers. Commuted-GEMM: h[n] = (sum_e g[e,k] x[col e]) . W1.
// R8 -> R9: fuse gather + MFMA GEMM per layer (s-tile lives in 12.8 KB LDS as fp16,
// strides 200/104 halves -> bank-uniform; R6's failed fusion used 25 KB fp32 LDS).
// Gauss computed inline from p (kills prep's gauss leg + gaussh array; redundant exp
// is idle-VALU). Pipeline: setup (x-cast + W-pack) -> fused<64,32> -> fused<32,16>.

#define KK 3

using half8   = __attribute__((ext_vector_type(8))) _Float16;
using float4v = __attribute__((ext_vector_type(4))) float;

// x fp32 -> fp16, and pack W1/W2 into MFMA B-fragment order (fp16):
// Bpack[((ot*KB+kb)*64+lane)*8+j] = W[kb*32+(lane>>4)*8+j][ot*16+(lane&15)]
__global__ void setup_kernel(const float* __restrict__ x, __half* __restrict__ xh,
                             const float* __restrict__ W1, const float* __restrict__ W2,
                             __half* __restrict__ B1, __half* __restrict__ B2, int NX8) {
    int t = blockIdx.x * blockDim.x + threadIdx.x;
    if (t < NX8) {
        float4 v0 = ((const float4*)x)[2 * t];
        float4 v1 = ((const float4*)x)[2 * t + 1];
        union { __half h[8]; float4 v; } o;
        o.h[0] = __float2half(v0.x); o.h[1] = __float2half(v0.y);
        o.h[2] = __float2half(v0.z); o.h[3] = __float2half(v0.w);
        o.h[4] = __float2half(v1.x); o.h[5] = __float2half(v1.y);
        o.h[6] = __float2half(v1.z); o.h[7] = __float2half(v1.w);
        ((float4*)xh)[t] = o.v;
    }
    if (t < 6144) {                    // W1: J=192 (KB=6), H=32 (OT=2)
        int j = t & 7, lane = (t >> 3) & 63, grp = t >> 9;   // grp = ot*6+kb
        int ot = grp / 6, kb = grp % 6;
        int kidx = kb * 32 + (lane >> 4) * 8 + j;
        B1[t] = __float2half(W1[kidx * 32 + ot * 16 + (lane & 15)]);
    } else if (t < 6144 + 1536) {      // W2: J=96 (KB=3), H=16 (OT=1)
        int t2 = t - 6144;
        int j = t2 & 7, lane = (t2 >> 3) & 63, kb = t2 >> 9;
        int kidx = kb * 32 + (lane >> 4) * 8 + j;
        B2[t2] = __float2half(W2[kidx * 16 + (lane & 15)]);
    }
}

__device__ __forceinline__ void unpack8(float4 raw, float* f) {
    union { float4 v; __half2 h2[4]; } u;
    u.v = raw;
#pragma unroll
    for (int q = 0; q < 4; ++q) {
        float2 t = __half22float2(u.h2[q]);
        f[2 * q] = t.x; f[2 * q + 1] = t.y;
    }
}

// Phase 1 (gather): thread = (node nl, 8-feature chunk ch); fp32 accum; gauss inline.
// s-tile -> LDS fp16, row stride STRIDE halves (bank-uniform for both write & A-read).
// Phase 2 (MFMA): wave = one 16-node x 16-output tile; A from LDS, B pre-packed (L1).
template <int F, int H, bool OUT_HALF>
__global__ __launch_bounds__(256) void fused_layer(
    const int* __restrict__ row_ptr, const int* __restrict__ col_idx,
    const float* __restrict__ p, const float* __restrict__ mu, const float* __restrict__ sigma,
    const __half* __restrict__ xh, const __half* __restrict__ Bpack,
    void* __restrict__ yout, int N) {
    constexpr int TPN    = F / 8;            // 8 / 4
    constexpr int NODES  = 256 / TPN;        // 32 / 64
    constexpr int J      = KK * F;           // 192 / 96
    constexpr int STRIDE = (F == 64) ? 200 : 104;  // halves; bank-uniform pad
    constexpr int KB     = J / 32;           // 6 / 3
    constexpr int OT     = H / 16;           // 2 / 1
    constexpr int TILES  = NODES / 16;       // 2 / 4   (TILES*OT == 4 waves)

    __shared__ __align__(16) __half sLh[NODES * STRIDE];

    const int tid = threadIdx.x;
    const int nl  = tid / TPN;
    const int ch  = tid % TPN;
    const int n   = blockIdx.x * NODES + nl;

    // per-kernel Gaussian constants (L1-resident)
    float gm0[KK], gm1[KK], iv0[KK], iv1[KK];
#pragma unroll
    for (int k = 0; k < KK; ++k) {
        gm0[k] = mu[2 * k];     gm1[k] = mu[2 * k + 1];
        float s0 = sigma[2 * k], s1 = sigma[2 * k + 1];
        iv0[k] = 1.f / (s0 * s0); iv1[k] = 1.f / (s1 * s1);
    }

    float a0[8], a1[8], a2[8];
#pragma unroll
    for (int q = 0; q < 8; ++q) { a0[q] = 0.f; a1[q] = 0.f; a2[q] = 0.f; }

    const float4* x4 = (const float4*)xh;
    const float2* p2 = (const float2*)p;

    if (n < N) {
        int e0 = row_ptr[n], e1 = row_ptr[n + 1];
        int e = e0;
        for (; e + 8 <= e1; e += 8) {
            int cols[8];
            float2 pv[8];
            float4 xr[8];
#pragma unroll
            for (int j = 0; j < 8; ++j) cols[j] = col_idx[e + j];
#pragma unroll
            for (int j = 0; j < 8; ++j) pv[j] = p2[e + j];
#pragma unroll
            for (int j = 0; j < 8; ++j) xr[j] = x4[(size_t)cols[j] * TPN + ch];
#pragma unroll
            for (int j = 0; j < 8; ++j) {
                float d00 = pv[j].x - gm0[0], d01 = pv[j].y - gm1[0];
                float d10 = pv[j].x - gm0[1], d11 = pv[j].y - gm1[1];
                float d20 = pv[j].x - gm0[2], d21 = pv[j].y - gm1[2];
                float g0 = __expf(-0.5f * (d00 * d00 * iv0[0] + d01 * d01 * iv1[0]));
                float g1 = __expf(-0.5f * (d10 * d10 * iv0[1] + d11 * d11 * iv1[1]));
                float g2 = __expf(-0.5f * (d20 * d20 * iv0[2] + d21 * d21 * iv1[2]));
                float f[8];
                unpack8(xr[j], f);
#pragma unroll
                for (int q = 0; q < 8; ++q) {
                    a0[q] = fmaf(g0, f[q], a0[q]);
                    a1[q] = fmaf(g1, f[q], a1[q]);
                    a2[q] = fmaf(g2, f[q], a2[q]);
                }
            }
        }
        for (; e < e1; ++e) {
            int c = col_idx[e];
            float2 pv = p2[e];
            float d00 = pv.x - gm0[0], d01 = pv.y - gm1[0];
            float d10 = pv.x - gm0[1], d11 = pv.y - gm1[1];
            float d20 = pv.x - gm0[2], d21 = pv.y - gm1[2];
            float g0 = __expf(-0.5f * (d00 * d00 * iv0[0] + d01 * d01 * iv1[0]));
            float g1 = __expf(-0.5f * (d10 * d10 * iv0[1] + d11 * d11 * iv1[1]));
            float g2 = __expf(-0.5f * (d20 * d20 * iv0[2] + d21 * d21 * iv1[2]));
            float f[8];
            unpack8(x4[(size_t)c * TPN + ch], f);
#pragma unroll
            for (int q = 0; q < 8; ++q) {
                a0[q] = fmaf(g0, f[q], a0[q]);
                a1[q] = fmaf(g1, f[q], a1[q]);
                a2[q] = fmaf(g2, f[q], a2[q]);
            }
        }
    }

    // dump s-tile to LDS (fp16). Write banks: base 4*(nl+ch) mod 32 -> 8 lanes/4-bank group.
    {
        union { __half h[8]; half8 v; } o;
#pragma unroll
        for (int q = 0; q < 8; ++q) o.h[q] = __float2half(a0[q]);
        *(half8*)(sLh + nl * STRIDE + 0 * F + ch * 8) = o.v;
#pragma unroll
        for (int q = 0; q < 8; ++q) o.h[q] = __float2half(a1[q]);
        *(half8*)(sLh + nl * STRIDE + 1 * F + ch * 8) = o.v;
#pragma unroll
        for (int q = 0; q < 8; ++q) o.h[q] = __float2half(a2[q]);
        *(half8*)(sLh + nl * STRIDE + 2 * F + ch * 8) = o.v;
    }
    __syncthreads();

    // phase 2: wave -> (node-tile, output-tile). 4 waves == TILES*OT tasks.
    {
        const int wv   = tid >> 6;
        const int lane = tid & 63;
        const int tile = wv / OT;
        const int ot   = wv % OT;
        const int n0   = blockIdx.x * NODES + tile * 16;
        if (n0 < N) {
            const int quad = lane >> 4;
            const int m    = lane & 15;      // A row / C col

            half8 b[KB];
#pragma unroll
            for (int kb = 0; kb < KB; ++kb)
                b[kb] = ((const half8*)Bpack)[(ot * KB + kb) * 64 + lane];

            const half8* av = (const half8*)(sLh + (size_t)(tile * 16 + m) * STRIDE);
            float4v acc = {0.f, 0.f, 0.f, 0.f};
#pragma unroll
            for (int kb = 0; kb < KB; ++kb)
                acc = __builtin_amdgcn_mfma_f32_16x16x32_f16(av[kb * 4 + quad], b[kb], acc, 0, 0, 0);

            // C/D: col = lane&15 (output), row = quad*4+reg (node)
#pragma unroll
            for (int reg = 0; reg < 4; ++reg) {
                int nn = n0 + quad * 4 + reg;
                if (nn < N) {
                    if constexpr (OUT_HALF)
                        ((__half*)yout)[(size_t)nn * H + ot * 16 + m] = __float2half(acc[reg]);
                    else
                        ((float*)yout)[(size_t)nn * H + m] = acc[reg];
                }
            }
        }
    }
}

extern "C" void kernel_launch(void* const* d_in, const int* in_sizes, int n_in,
                              void* d_out, int out_size, void* d_ws, size_t ws_size,
                              hipStream_t stream) {
    const int* row_ptr  = (const int*)d_in[0];
    const int* col_idx  = (const int*)d_in[1];
    const float* x      = (const float*)d_in[2];
    const float* p      = (const float*)d_in[3];
    const float* mu     = (const float*)d_in[4];
    const float* sigma  = (const float*)d_in[5];
    const float* W1     = (const float*)d_in[6];
    const float* W2     = (const float*)d_in[7];

    const int N = in_sizes[0] - 1;

    __half* B1pack = (__half*)d_ws;                 // 6144 halves
    __half* B2pack = B1pack + 6144;                 // 1536 halves
    __half* xh     = B2pack + 1536;                 // N*64 fp16
    __half* hh     = xh + (size_t)N * 64;           // N*32 fp16
    float*  out    = (float*)d_out;                 // N*16 f32

    const int B = 256;
    const int NX8 = N * 8;
    const int setup_n = (NX8 > 7680 ? NX8 : 7680);

    setup_kernel<<<(setup_n + B - 1) / B, B, 0, stream>>>(x, xh, W1, W2, B1pack, B2pack, NX8);

    fused_layer<64, 32, true><<<(N + 31) / 32, B, 0, stream>>>(
        row_ptr, col_idx, p, mu, sigma, xh, B1pack, (void*)hh, N);
    fused_layer<32, 16, false><<<(N + 63) / 64, B, 0, stream>>>(
        row_ptr, col_idx, p, mu, sigma, hh, B2pack, (void*)out, N);
}

// Round 10
// 156.178 us; speedup vs baseline: 1.7874x; 1.0040x over previous
//
#include <hip/hip_runtime.h>
#include <hip/hip_fp16.h>

// GMM (MoNet) graph conv, 2 layers. Commuted-GEMM: h[n] = (sum_e g[e,k] x[col e]) . W1.
// R9 -> R10: gauss moved OUT of the gather loop back to setup (R9 computed it inline,
// redundantly per TPN=8 threads -> ~376 VALU instrs between load batches, throttling the
// gather to ~2.4 TB/s vs R3's measured 5.5 TB/s for a load-dense loop). Gather loop is
// again: 8 col + 8 gauss(8B) + 8 xh(16B) loads, then cvt+FMA only.
// Pipeline: setup (gauss + x-cast + W-pack) -> fused<64,32> -> fused<32,16>.

#define KK 3

using half8   = __attribute__((ext_vector_type(8))) _Float16;
using float4v = __attribute__((ext_vector_type(4))) float;

// gauss (fp16 half4 per edge), x fp32->fp16, W1/W2 -> MFMA B-fragment order (fp16).
__global__ void setup_kernel(const float* __restrict__ p, const float* __restrict__ mu,
                             const float* __restrict__ sigma, float2* __restrict__ gaussh,
                             const float* __restrict__ x, __half* __restrict__ xh,
                             const float* __restrict__ W1, const float* __restrict__ W2,
                             __half* __restrict__ B1, __half* __restrict__ B2,
                             int E, int NX8) {
    int t = blockIdx.x * blockDim.x + threadIdx.x;
    if (t < E) {
        float p0 = p[2 * t], p1 = p[2 * t + 1];
        float g[KK];
#pragma unroll
        for (int k = 0; k < KK; ++k) {
            float m0 = mu[2 * k], m1 = mu[2 * k + 1];
            float s0 = sigma[2 * k], s1 = sigma[2 * k + 1];
            float d0 = p0 - m0, d1 = p1 - m1;
            float q = (d0 * d0) / (s0 * s0) + (d1 * d1) / (s1 * s1);
            g[k] = __expf(-0.5f * q);
        }
        union { __half h[4]; float2 v; } o;
        o.h[0] = __float2half(g[0]); o.h[1] = __float2half(g[1]);
        o.h[2] = __float2half(g[2]); o.h[3] = __float2half(0.f);
        gaussh[t] = o.v;
    }
    if (t < NX8) {
        float4 v0 = ((const float4*)x)[2 * t];
        float4 v1 = ((const float4*)x)[2 * t + 1];
        union { __half h[8]; float4 v; } o;
        o.h[0] = __float2half(v0.x); o.h[1] = __float2half(v0.y);
        o.h[2] = __float2half(v0.z); o.h[3] = __float2half(v0.w);
        o.h[4] = __float2half(v1.x); o.h[5] = __float2half(v1.y);
        o.h[6] = __float2half(v1.z); o.h[7] = __float2half(v1.w);
        ((float4*)xh)[t] = o.v;
    }
    if (t < 6144) {                    // W1: J=192 (KB=6), H=32 (OT=2)
        int j = t & 7, lane = (t >> 3) & 63, grp = t >> 9;   // grp = ot*6+kb
        int ot = grp / 6, kb = grp % 6;
        int kidx = kb * 32 + (lane >> 4) * 8 + j;
        B1[t] = __float2half(W1[kidx * 32 + ot * 16 + (lane & 15)]);
    } else if (t < 6144 + 1536) {      // W2: J=96 (KB=3), H=16 (OT=1)
        int t2 = t - 6144;
        int j = t2 & 7, lane = (t2 >> 3) & 63, kb = t2 >> 9;
        int kidx = kb * 32 + (lane >> 4) * 8 + j;
        B2[t2] = __float2half(W2[kidx * 16 + (lane & 15)]);
    }
}

__device__ __forceinline__ void unpack8(float4 raw, float* f) {
    union { float4 v; __half2 h2[4]; } u;
    u.v = raw;
#pragma unroll
    for (int q = 0; q < 4; ++q) {
        float2 t = __half22float2(u.h2[q]);
        f[2 * q] = t.x; f[2 * q + 1] = t.y;
    }
}

// Phase 1 (gather): thread = (node nl, 8-feature chunk ch); fp32 accum; lean loop.
// s-tile -> LDS fp16, row stride STRIDE halves (bank-uniform write & A-read).
// Phase 2 (MFMA): wave = one 16-node x 16-output tile; A from LDS, B pre-packed (L1).
template <int F, int H, bool OUT_HALF>
__global__ __launch_bounds__(256) void fused_layer(
    const int* __restrict__ row_ptr, const int* __restrict__ col_idx,
    const float2* __restrict__ gaussh, const __half* __restrict__ xh,
    const __half* __restrict__ Bpack, void* __restrict__ yout, int N) {
    constexpr int TPN    = F / 8;            // 8 / 4
    constexpr int NODES  = 256 / TPN;        // 32 / 64
    constexpr int J      = KK * F;           // 192 / 96
    constexpr int STRIDE = (F == 64) ? 200 : 104;  // halves
    constexpr int KB     = J / 32;           // 6 / 3
    constexpr int OT     = H / 16;           // 2 / 1

    __shared__ __align__(16) __half sLh[NODES * STRIDE];

    const int tid = threadIdx.x;
    const int nl  = tid / TPN;
    const int ch  = tid % TPN;
    const int n   = blockIdx.x * NODES + nl;

    float a0[8], a1[8], a2[8];
#pragma unroll
    for (int q = 0; q < 8; ++q) { a0[q] = 0.f; a1[q] = 0.f; a2[q] = 0.f; }

    const float4* x4 = (const float4*)xh;

    if (n < N) {
        int e0 = row_ptr[n], e1 = row_ptr[n + 1];
        int e = e0;
        for (; e + 8 <= e1; e += 8) {
            int cols[8];
            float2 gr[8];
            float4 xr[8];
#pragma unroll
            for (int j = 0; j < 8; ++j) cols[j] = col_idx[e + j];
#pragma unroll
            for (int j = 0; j < 8; ++j) gr[j] = gaussh[e + j];
#pragma unroll
            for (int j = 0; j < 8; ++j) xr[j] = x4[(size_t)cols[j] * TPN + ch];
#pragma unroll
            for (int j = 0; j < 8; ++j) {
                union { float2 v; __half2 h2[2]; } ug; ug.v = gr[j];
                float2 gab = __half22float2(ug.h2[0]);
                float2 gc_ = __half22float2(ug.h2[1]);
                float f[8];
                unpack8(xr[j], f);
#pragma unroll
                for (int q = 0; q < 8; ++q) {
                    a0[q] = fmaf(gab.x, f[q], a0[q]);
                    a1[q] = fmaf(gab.y, f[q], a1[q]);
                    a2[q] = fmaf(gc_.x, f[q], a2[q]);
                }
            }
        }
        for (; e < e1; ++e) {
            int c = col_idx[e];
            union { float2 v; __half2 h2[2]; } ug; ug.v = gaussh[e];
            float2 gab = __half22float2(ug.h2[0]);
            float2 gc_ = __half22float2(ug.h2[1]);
            float f[8];
            unpack8(x4[(size_t)c * TPN + ch], f);
#pragma unroll
            for (int q = 0; q < 8; ++q) {
                a0[q] = fmaf(gab.x, f[q], a0[q]);
                a1[q] = fmaf(gab.y, f[q], a1[q]);
                a2[q] = fmaf(gc_.x, f[q], a2[q]);
            }
        }
    }

    // dump s-tile to LDS (fp16)
    {
        union { __half h[8]; half8 v; } o;
#pragma unroll
        for (int q = 0; q < 8; ++q) o.h[q] = __float2half(a0[q]);
        *(half8*)(sLh + nl * STRIDE + 0 * F + ch * 8) = o.v;
#pragma unroll
        for (int q = 0; q < 8; ++q) o.h[q] = __float2half(a1[q]);
        *(half8*)(sLh + nl * STRIDE + 1 * F + ch * 8) = o.v;
#pragma unroll
        for (int q = 0; q < 8; ++q) o.h[q] = __float2half(a2[q]);
        *(half8*)(sLh + nl * STRIDE + 2 * F + ch * 8) = o.v;
    }
    __syncthreads();

    // phase 2: wave -> (node-tile, output-tile)
    {
        const int wv   = tid >> 6;
        const int lane = tid & 63;
        const int tile = wv / OT;
        const int ot   = wv % OT;
        const int n0   = blockIdx.x * NODES + tile * 16;
        if (n0 < N) {
            const int quad = lane >> 4;
            const int m    = lane & 15;

            half8 b[KB];
#pragma unroll
            for (int kb = 0; kb < KB; ++kb)
                b[kb] = ((const half8*)Bpack)[(ot * KB + kb) * 64 + lane];

            const half8* av = (const half8*)(sLh + (size_t)(tile * 16 + m) * STRIDE);
            float4v acc = {0.f, 0.f, 0.f, 0.f};
#pragma unroll
            for (int kb = 0; kb < KB; ++kb)
                acc = __builtin_amdgcn_mfma_f32_16x16x32_f16(av[kb * 4 + quad], b[kb], acc, 0, 0, 0);

            // C/D: col = lane&15 (output), row = quad*4+reg (node)
#pragma unroll
            for (int reg = 0; reg < 4; ++reg) {
                int nn = n0 + quad * 4 + reg;
                if (nn < N) {
                    if constexpr (OUT_HALF)
                        ((__half*)yout)[(size_t)nn * H + ot * 16 + m] = __float2half(acc[reg]);
                    else
                        ((float*)yout)[(size_t)nn * H + m] = acc[reg];
                }
            }
        }
    }
}

extern "C" void kernel_launch(void* const* d_in, const int* in_sizes, int n_in,
                              void* d_out, int out_size, void* d_ws, size_t ws_size,
                              hipStream_t stream) {
    const int* row_ptr  = (const int*)d_in[0];
    const int* col_idx  = (const int*)d_in[1];
    const float* x      = (const float*)d_in[2];
    const float* p      = (const float*)d_in[3];
    const float* mu     = (const float*)d_in[4];
    const float* sigma  = (const float*)d_in[5];
    const float* W1     = (const float*)d_in[6];
    const float* W2     = (const float*)d_in[7];

    const int N = in_sizes[0] - 1;
    const int E = in_sizes[1];

    float2* gaussh = (float2*)d_ws;                  // E * 8 B
    __half* B1pack = (__half*)(gaussh + (size_t)E);  // 6144 halves
    __half* B2pack = B1pack + 6144;                  // 1536 halves
    __half* xh     = B2pack + 1536;                  // N*64 fp16
    __half* hh     = xh + (size_t)N * 64;            // N*32 fp16
    float*  out    = (float*)d_out;                  // N*16 f32

    const int B = 256;
    const int NX8 = N * 8;
    int setup_n = E > NX8 ? E : NX8;
    if (setup_n < 7680) setup_n = 7680;

    setup_kernel<<<(setup_n + B - 1) / B, B, 0, stream>>>(
        p, mu, sigma, gaussh, x, xh, W1, W2, B1pack, B2pack, E, NX8);

    fused_layer<64, 32, true><<<(N + 31) / 32, B, 0, stream>>>(
        row_ptr, col_idx, gaussh, xh, B1pack, (void*)hh, N);
    fused_layer<32, 16, false><<<(N + 63) / 64, B, 0, stream>>>(
        row_ptr, col_idx, gaussh, hh, B2pack, (void*)out, N);
}